// Round 3
// baseline (1560.091 us; speedup 1.0000x reference)
//
#include <hip/hip_runtime.h>
#include <cstdint>
#include <cstddef>

typedef unsigned short u16;
typedef unsigned int u32;
typedef __attribute__((ext_vector_type(8))) _Float16 half8;   // 8 x f16 MFMA frag
typedef __attribute__((ext_vector_type(4))) float floatx4;    // MFMA acc / vector store
typedef __attribute__((ext_vector_type(8))) u16 u16x8;

#define H_ 16
#define S_ 4096
#define D_ 64
#define BM 64
#define BN 64
#define MBW (S_ / 32)          // 128 mask words per row
#define HSTRIDE (S_ * D_)      // 262144 elements per head

__device__ __forceinline__ u16 f2h(float x) {
  union { _Float16 h; u16 u; } c;
  c.h = (_Float16)x;           // v_cvt_f16_f32, RNE
  return c.u;
}

__device__ __forceinline__ half8 ld16(const u16* p) {
  return *(const half8*)p;     // 16B vector load (ds or global)
}

__device__ __forceinline__ void st_attn8(float* __restrict__ p, half8 v) {
  floatx4 f0 = { (float)v[0], (float)v[1], (float)v[2], (float)v[3] };
  floatx4 f1 = { (float)v[4], (float)v[5], (float)v[6], (float)v[7] };
  __builtin_nontemporal_store(f0, (floatx4*)p);
  __builtin_nontemporal_store(f1, (floatx4*)(p + 4));
}

// ---- prep: fp32 Q -> f16 linear copy ----
__global__ void prep_q(const float* __restrict__ q, u16* __restrict__ qb) {
  size_t idx = ((size_t)blockIdx.x * 256 + threadIdx.x) * 8;
  float4 f0 = *(const float4*)(q + idx);
  float4 f1 = *(const float4*)(q + idx + 4);
  u16x8 o;
  o[0] = f2h(f0.x); o[1] = f2h(f0.y); o[2] = f2h(f0.z); o[3] = f2h(f0.w);
  o[4] = f2h(f1.x); o[5] = f2h(f1.y); o[6] = f2h(f1.z); o[7] = f2h(f1.w);
  *(u16x8*)(qb + idx) = o;
}

// ---- prep: fp32 K [H][S][D] -> f16 fragment-major kf ----
// kf[h][J=s>>4][half=d>>5][quad=(d>>3)&3][lrow=s&15][e=d&7]
// so a wave's B-frag load is base + lane*8 (fully coalesced 16B/lane).
__global__ void prep_kf(const float* __restrict__ k, u16* __restrict__ kf) {
  size_t idx = ((size_t)blockIdx.x * 256 + threadIdx.x) * 8;
  int h = (int)(idx >> 18);            // / (S*D)
  int rem = (int)(idx & (HSTRIDE - 1));
  int s = rem >> 6, d = rem & 63;      // d is a multiple of 8
  float4 f0 = *(const float4*)(k + idx);
  float4 f1 = *(const float4*)(k + idx + 4);
  u16x8 o;
  o[0] = f2h(f0.x); o[1] = f2h(f0.y); o[2] = f2h(f0.z); o[3] = f2h(f0.w);
  o[4] = f2h(f1.x); o[5] = f2h(f1.y); o[6] = f2h(f1.z); o[7] = f2h(f1.w);
  size_t off = ((size_t)(h * 256 + (s >> 4))) * 1024
             + (size_t)(d >> 5) * 512 + (size_t)((d >> 3) & 3) * 128 + (size_t)(s & 15) * 8;
  *(u16x8*)(kf + off) = o;
}

// ---- prep: fp32 V [H][S][D] -> f16 fragment-major vf (transposed) ----
// vf[h][jt=j>>6][c=d>>4][half=(j&63)>>5][quad=((j&63)>>3)&3][lrow=d&15][e=j&7]
// = V^T(d, j); B-frag load for PV is base + lane*8.
__global__ void prep_vf(const float* __restrict__ v, u16* __restrict__ vf) {
  __shared__ float tile[64][65];
  int h = blockIdx.y, s0 = blockIdx.x * 64;
  int t = threadIdx.x;
  int r = t >> 2, c0 = (t & 3) * 16;
  const float* src = v + ((size_t)(h * S_ + s0 + r)) * D_ + c0;
  #pragma unroll
  for (int i = 0; i < 16; i += 4) {
    float4 f = *(const float4*)(src + i);
    tile[r][c0 + i + 0] = f.x; tile[r][c0 + i + 1] = f.y;
    tile[r][c0 + i + 2] = f.z; tile[r][c0 + i + 3] = f.w;
  }
  __syncthreads();
  // thread (r, c0) emits V^T(d=r, j=s0+c0+i), i=0..7 (o0) and i=8..15 (o1)
  u16x8 o0, o1;
  #pragma unroll
  for (int i = 0; i < 8; i++) o0[i] = f2h(tile[c0 + i][r]);
  #pragma unroll
  for (int i = 0; i < 8; i++) o1[i] = f2h(tile[c0 + 8 + i][r]);
  int c = r >> 4, lrow = r & 15;
  int half = c0 >> 5, quad = (c0 >> 3) & 3;   // for o0; o1 is quad+1 (same half)
  u16* base = vf + (size_t)h * HSTRIDE + (size_t)blockIdx.x * 4096
            + (size_t)c * 1024 + (size_t)lrow * 8;
  *(u16x8*)(base + half * 512 + quad * 128) = o0;
  *(u16x8*)(base + half * 512 + (quad + 1) * 128) = o1;
}

// ---- prep: int32 mask [S][S] -> bitmask [S][S/32] ----
__global__ void prep_mask(const int* __restrict__ mask, u32* __restrict__ mb) {
  size_t widx = (size_t)blockIdx.x * 256 + threadIdx.x;
  const int* src = mask + widx * 32;
  u32 bits = 0;
  #pragma unroll
  for (int i = 0; i < 8; i++) {
    int4 m4 = *(const int4*)(src + i * 4);
    bits |= (m4.x != 0 ? 1u : 0u) << (i * 4 + 0);
    bits |= (m4.y != 0 ? 1u : 0u) << (i * 4 + 1);
    bits |= (m4.z != 0 ? 1u : 0u) << (i * 4 + 2);
    bits |= (m4.w != 0 ? 1u : 0u) << (i * 4 + 3);
  }
  mb[widx] = bits;
}

// ---- fused attention, ZERO barriers ----
// pass1: row sums of mask-gated exp(scores); pass2: recompute, write attn, PV.
// K/V fragments come straight from L1/L2 (fragment-major layout, coalesced).
// Ps is a wave-private LDS slab (C-layout -> A-layout transpose), no sync needed.
__global__ __launch_bounds__(256, 4)
void attn_fused(const u16* __restrict__ qb, const u16* __restrict__ kf,
                const u16* __restrict__ vf, const u32* __restrict__ mb,
                float* __restrict__ out, float* __restrict__ attn) {
  __shared__ __align__(16) u16 Ps[BM * BN];

  const int h = blockIdx.y;
  const int row0 = blockIdx.x * BM;
  const int tid = threadIdx.x;
  const int wave = tid >> 6;
  const int lane = tid & 63;
  const int lrow = lane & 15;
  const int quad = lane >> 4;
  const int lr0 = wave * 16 + quad * 4;   // C-layout row base (+r)
  const int swb = lrow & 7;
  const int ch0 = (quad ^ swb) << 3;      // swizzled u16 offset of chunk `quad`
  const int ch1 = ((quad + 4) ^ swb) << 3;
  const int colc = lrow & 7;
  const int colh = lrow >> 3;

  // Q fragments straight from global, once (A-frag: row=lane&15, k=quad*8+j)
  const u16* qrow = qb + ((size_t)h * S_ + row0 + wave * 16 + lrow) * D_;
  const half8 a0 = ld16(qrow + quad * 8);
  const half8 a1 = ld16(qrow + 32 + quad * 8);

  const u16* kfh = kf + (size_t)h * HSTRIDE;
  const u16* vfh = vf + (size_t)h * HSTRIDE;
  const int loff = lane * 8;

  // ---------- pass 1: row sums of mask-gated exp(scores) ----------
  float rsum[4] = {0.f, 0.f, 0.f, 0.f};
  for (int j0 = 0; j0 < S_; j0 += BN) {
    const u16* kJ = kfh + (size_t)(j0 >> 4) * 1024;   // J block for c=0
    half8 kb0[4], kb1[4];
    #pragma unroll
    for (int c = 0; c < 4; c++) {
      kb0[c] = ld16(kJ + c * 1024 + loff);
      kb1[c] = ld16(kJ + c * 1024 + 512 + loff);
    }
    u32 mwx[4], mwy[4];
    #pragma unroll
    for (int r = 0; r < 4; r++) {
      const u32* mp = mb + (size_t)(row0 + lr0 + r) * MBW + (j0 >> 5);
      uint2 w = *(const uint2*)mp;
      mwx[r] = w.x; mwy[r] = w.y;
    }
    #pragma unroll
    for (int c = 0; c < 4; c++) {
      floatx4 sc = {0.f, 0.f, 0.f, 0.f};
      sc = __builtin_amdgcn_mfma_f32_16x16x32_f16(a0, kb0[c], sc, 0, 0, 0);
      sc = __builtin_amdgcn_mfma_f32_16x16x32_f16(a1, kb1[c], sc, 0, 0, 0);
      const int sh = (c & 1) * 16 + lrow;
      #pragma unroll
      for (int r = 0; r < 4; r++) {
        u32 w = (c < 2) ? mwx[r] : mwy[r];
        rsum[r] += ((w >> sh) & 1u) ? __expf(sc[r]) : 0.f;
      }
    }
  }
  // butterfly leaves the full row sum in EVERY lane of the 16-lane group
  float linv[4];
  #pragma unroll
  for (int r = 0; r < 4; r++) {
    float s = rsum[r];
    s += __shfl_xor(s, 1);
    s += __shfl_xor(s, 2);
    s += __shfl_xor(s, 4);
    s += __shfl_xor(s, 8);
    linv[r] = 1.0f / s;
  }

  // ---------- pass 2: recompute scores, write attn from P-frags, accumulate PV ----------
  floatx4 acc[4];
  #pragma unroll
  for (int c = 0; c < 4; c++) acc[c] = (floatx4){0.f, 0.f, 0.f, 0.f};

  float* attnh = attn + (size_t)h * S_ * S_;

  for (int j0 = 0; j0 < S_; j0 += BN) {
    const u16* kJ = kfh + (size_t)(j0 >> 4) * 1024;
    const u16* vJ = vfh + (size_t)(j0 >> 6) * 4096;
    half8 kb0[4], kb1[4], vb0[4], vb1[4];
    #pragma unroll
    for (int c = 0; c < 4; c++) {
      kb0[c] = ld16(kJ + c * 1024 + loff);
      kb1[c] = ld16(kJ + c * 1024 + 512 + loff);
    }
    #pragma unroll
    for (int c = 0; c < 4; c++) {          // issued early, consumed after exp phase
      vb0[c] = ld16(vJ + c * 1024 + loff);
      vb1[c] = ld16(vJ + c * 1024 + 512 + loff);
    }
    u32 mwx[4], mwy[4];
    #pragma unroll
    for (int r = 0; r < 4; r++) {
      const u32* mp = mb + (size_t)(row0 + lr0 + r) * MBW + (j0 >> 5);
      uint2 w = *(const uint2*)mp;
      mwx[r] = w.x; mwy[r] = w.y;
    }
    #pragma unroll
    for (int c = 0; c < 4; c++) {
      floatx4 sc = {0.f, 0.f, 0.f, 0.f};
      sc = __builtin_amdgcn_mfma_f32_16x16x32_f16(a0, kb0[c], sc, 0, 0, 0);
      sc = __builtin_amdgcn_mfma_f32_16x16x32_f16(a1, kb1[c], sc, 0, 0, 0);
      const int sh = (c & 1) * 16 + lrow;
      #pragma unroll
      for (int r = 0; r < 4; r++) {
        u32 w = (c < 2) ? mwx[r] : mwy[r];
        float p = ((w >> sh) & 1u) ? __expf(sc[r]) * linv[r] : 0.f;
        const int prow = lr0 + r;          // wave-private 16-row slab of Ps
        Ps[prow * 64 + (((2 * c + colh) ^ (prow & 7)) << 3) + colc] = f2h(p);
      }
    }
    // same-wave write->read: lgkmcnt ordering (compiler-inserted) suffices, no barrier
    const u16* prow = Ps + (wave * 16 + lrow) * 64;
    half8 p0 = ld16(prow + ch0);           // A-frag k=quad*8+e (cols 0..31)
    half8 p1 = ld16(prow + ch1);           // cols 32..63
    float* arow = attnh + (size_t)(row0 + wave * 16 + lrow) * S_ + j0 + quad * 8;
    st_attn8(arow, p0);
    st_attn8(arow + 32, p1);
    #pragma unroll
    for (int c = 0; c < 4; c++) {
      acc[c] = __builtin_amdgcn_mfma_f32_16x16x32_f16(p0, vb0[c], acc[c], 0, 0, 0);
      acc[c] = __builtin_amdgcn_mfma_f32_16x16x32_f16(p1, vb1[c], acc[c], 0, 0, 0);
    }
  }

  #pragma unroll
  for (int c = 0; c < 4; c++) {
    #pragma unroll
    for (int r = 0; r < 4; r++) {
      out[((size_t)(h * S_ + row0 + lr0 + r)) * D_ + c * 16 + lrow] = acc[c][r];
    }
  }
}

extern "C" void kernel_launch(void* const* d_in, const int* in_sizes, int n_in,
                              void* d_out, int out_size, void* d_ws, size_t ws_size,
                              hipStream_t stream) {
  const float* q = (const float*)d_in[0];
  const float* k = (const float*)d_in[1];
  const float* v = (const float*)d_in[2];
  const int* mask = (const int*)d_in[3];
  float* out = (float*)d_out;
  float* attn = out + (size_t)H_ * S_ * D_;

  const size_t N = (size_t)H_ * S_ * D_;   // 4,194,304 elements per tensor
  u16* qb = (u16*)d_ws;                    // f16 Q [H][S][D]
  u16* kfb = qb + N;                       // f16 K fragment-major
  u16* vfb = kfb + N;                      // f16 V^T fragment-major
  u32* mb = (u32*)(vfb + N);               // bitmask [S][S/32] (2 MB)

  prep_q<<<dim3((unsigned)(N / (256 * 8))), 256, 0, stream>>>(q, qb);
  prep_kf<<<dim3((unsigned)(N / (256 * 8))), 256, 0, stream>>>(k, kfb);
  prep_vf<<<dim3(S_ / 64, H_), 256, 0, stream>>>(v, vfb);
  prep_mask<<<dim3((unsigned)(((size_t)S_ * S_ / 32) / 256)), 256, 0, stream>>>(mask, mb);
  attn_fused<<<dim3(S_ / BM, H_), 256, 0, stream>>>(qb, kfb, vfb, mb, out, attn);
}